// Round 7
// baseline (2760.507 us; speedup 1.0000x reference)
//
#include <hip/hip_runtime.h>

// LTC RNN (LiquidNeuralNetwork): B=512, S=512, H=128, 2 layers, RK4.
// Round 9: 16 WAVES x 1 ROW-TILE (1024 threads) on the round-8 math.
// Round-8 counters: active SIMDs 54% VALU + 30% MFMA issue; rest latency/
// barrier idle with only 2-deep wave interleave. This round keeps per-SIMD
// issue constant but halves each wave's serial chain (8 MFMAs + 4 gate elems
// vs 16+8) and doubles wave depth (4/SIMD): latency hides under TLP (G1/G7).
// Waves 0-7 = L0 tiles 0-7 @t; waves 8-15 = L1 tiles 0-7 @t-1 (lag-1).
// Kept: packed-f32 gate math, gx/bg folded into MFMA C-init, lgkm-only
// barriers, x-proj pipelined into slot B, f16 fragment pack, 4 slots/step.

typedef _Float16 f16;
typedef _Float16 f16x4 __attribute__((ext_vector_type(4)));
typedef _Float16 f16x8 __attribute__((ext_vector_type(8)));
typedef float f32x2 __attribute__((ext_vector_type(2)));
typedef float f32x4 __attribute__((ext_vector_type(4)));

#define NSTEP 512
#define OFF_A0 0
#define OFF_A1 32768
#define OFF_AIO 65536
#define OFF_AX 98304
#define W_TOTAL 122880

// LDS byte offsets. hh buffers: [16 cols][136 f16] = 4352 B each.
#define HQ0 0
#define HQ1 4352
#define L0A 8704
#define L0B 13056
#define L1A 17408
#define L1B 21760
#define L1H 26112
#define XT0 30464
#define XT1 32768
#define SMEM_BYTES 35072

__device__ __forceinline__ float rcp_f(float x) { return __builtin_amdgcn_rcpf(x); }

#define FMA2(A, B, C) __builtin_elementwise_fma((A), (B), (C))
#define B2(X) ((f32x2){(X), (X)})
#define ZERO4 ((f32x4){0.f, 0.f, 0.f, 0.f})
#define ZERO2 ((f32x2){0.f, 0.f})

// packed tanh: pk add + 2 scalar exp + pk add + 2 rcp + pk fma
__device__ __forceinline__ f32x2 tanh2_f(f32x2 z) {
  f32x2 zz = z + z;
  f32x2 e = {__expf(zz[0]), __expf(zz[1])};
  f32x2 d = e + 1.f;
  f32x2 r = {rcp_f(d[0]), rcp_f(d[1])};
  return FMA2(r, B2(-2.f), B2(1.f));
}
// packed sigmoid(t), t in [-1,1]: odd Taylor of 0.5+0.5*tanh(t/2), |err|<3e-6
__device__ __forceinline__ f32x2 sig2_f(f32x2 t) {
  f32x2 s = t * t;
  f32x2 p = FMA2(s, B2(2.1356861e-5f), B2(-2.1081349e-4f));
  p = FMA2(s, p, B2(2.0833333e-3f));
  p = FMA2(s, p, B2(-2.0833333e-2f));
  p = FMA2(s, p, B2(0.25f));
  return FMA2(t, p, B2(0.5f));
}

// lgkm-only barrier: LDS produce->consume needs lgkmcnt(0)+s_barrier only;
// does NOT drain vmcnt (seq prefetch stays in flight across barriers).
#define BAR()                                            \
  do {                                                   \
    asm volatile("s_waitcnt lgkmcnt(0)" ::: "memory");   \
    __builtin_amdgcn_s_barrier();                        \
  } while (0)

// Pack all recurrent-loop weights into f16 MFMA A-fragments.
// A-frag (16x16x32): A[m=lane&15][k=(lane>>4)*8+j], row-tile T = rows 16T..16T+15.
// A0 @0      [T8][sel2][kc4][lane64][j8]  sel0=Wg0 h-part, sel1=Wrec0
// A1 @32768  same                          sel0=Wg1 h-part, sel1=Wrec1
// AIO@65536  same                          sel0=Win1,       sel1=Wg1 x-part
// AX @98304  [T8][sel2][kc3][lane64][j8]  sel0=Win0,       sel1=Wg0 x-part (K=96)
__global__ __launch_bounds__(256) void prep_kernel(
    const float* __restrict__ Win0, const float* __restrict__ Wrec0,
    const float* __restrict__ Wg0, const float* __restrict__ Win1,
    const float* __restrict__ Wrec1, const float* __restrict__ Wg1,
    f16* __restrict__ W) {
  int i = blockIdx.x * 256 + threadIdx.x;
  if (i >= W_TOTAL) return;
  if (i < OFF_AX) {
    int sec = i >> 15;
    int r = i & 32767;
    int j = r & 7, lane = (r >> 3) & 63, kc = (r >> 9) & 3, sel = (r >> 11) & 1,
        w = (r >> 12) & 7;
    int row = w * 16 + (lane & 15);
    int k = kc * 32 + ((lane >> 4) << 3) + j;
    float v;
    if (sec == 0)
      v = sel ? Wrec0[row * 128 + k] : Wg0[row * 224 + 96 + k];
    else if (sec == 1)
      v = sel ? Wrec1[row * 128 + k] : Wg1[row * 256 + 128 + k];
    else
      v = sel ? Wg1[row * 256 + k] : Win1[row * 128 + k];
    W[i] = (f16)v;
  } else {
    int r = i - OFF_AX;
    int j = r & 7, lane = (r >> 3) & 63, g = r >> 9;
    int kc = g % 3, sg = g / 3;
    int sel = sg & 1, w = sg >> 1;
    int row = w * 16 + (lane & 15);
    int k = kc * 32 + ((lane >> 4) << 3) + j;
    W[i] = (f16)(sel ? Wg0[row * 224 + k] : Win0[row * 96 + k]);
  }
}

#define MFMA16(A, B, C) __builtin_amdgcn_mfma_f32_16x16x32_f16((A), (B), (C), 0, 0, 0)

// recurrent matvec (1 tile), gx folded: ga = gx4 + Wg_h*h; ra = Wrec*h
#define MM2G(SRC)                                                   \
  {                                                                 \
    ga = gx4; ra = ZERO4;                                           \
    const f16* bp_ = (SRC) + c * 136 + 8 * q;                       \
    _Pragma("unroll") for (int kc_ = 0; kc_ < 4; ++kc_) {           \
      f16x8 bf_ = *(const f16x8*)(bp_ + kc_ * 32);                  \
      ga = MFMA16(awg[kc_], bf_, ga);                               \
      ra = MFMA16(awr[kc_], bf_, ra);                               \
    }                                                               \
  }

// L1 io projection (1 tile), bg folded: ga = Win1*h0; ra = bg + Wg1x*h0
#define MMIO_B(SRC)                                                 \
  {                                                                 \
    ga = ZERO4; ra = bgv4;                                          \
    const f16* bp_ = (SRC) + c * 136 + 8 * q;                       \
    _Pragma("unroll") for (int kc_ = 0; kc_ < 4; ++kc_) {           \
      f16x8 bf_ = *(const f16x8*)(bp_ + kc_ * 32);                  \
      ga = MFMA16(au[kc_], bf_, ga);                                \
      ra = MFMA16(ag2[kc_], bf_, ra);                               \
    }                                                               \
  }

// L0 x-projection (1 tile, K=96: 2 chunks from x-tile + ctx), bg folded:
// UD = Win0*x; GD = bg + Wg0x*x
#define XPROJ(XSRC, UD, GD)                                         \
  {                                                                 \
    f32x4 tg_ = ZERO4, tr_ = bgv4;                                  \
    f16x8 bx0_ = *(const f16x8*)((XSRC) + c * 72 + 8 * q);          \
    f16x8 bx1_ = *(const f16x8*)((XSRC) + c * 72 + 32 + 8 * q);     \
    tg_ = MFMA16(au[0], bx0_, tg_); tr_ = MFMA16(ag2[0], bx0_, tr_);\
    tg_ = MFMA16(au[1], bx1_, tg_); tr_ = MFMA16(ag2[1], bx1_, tr_);\
    tg_ = MFMA16(au[2], bctx, tg_); tr_ = MFMA16(ag2[2], bctx, tr_);\
    (UD) = tg_; (GD) = tr_;                                         \
  }

// RK stage body (1 tile), packed pairs. Gate arg complete in ga (gx folded).
// FIRST=1: ksum = kk (stage 1). Else ksum += WC*kk.
#define GATEP(WC, HC, DST, FIRST)                                   \
  {                                                                 \
    f16x4 hv_;                                                      \
    _Pragma("unroll") for (int p_ = 0; p_ < 2; ++p_) {              \
      f32x2 z_ = {ga[2 * p_], ga[2 * p_ + 1]};                      \
      f32x2 rr_ = {ra[2 * p_], ra[2 * p_ + 1]};                     \
      f32x2 th_ = tanh2_f(z_);                                      \
      f32x2 gt_ = sig2_f(th_);                                      \
      f32x2 kk_ = FMA2(gt_, rr_, FMA2(nitv2[p_], hhc2[p_], u2[p_])); \
      ksum2[p_] = (FIRST) ? kk_ : FMA2(B2(WC), kk_, ksum2[p_]);     \
      f32x2 hn_ = FMA2(B2(HC), kk_, hst2[p_]);                      \
      hhc2[p_] = hn_;                                               \
      hv_[2 * p_] = (f16)hn_[0];                                    \
      hv_[2 * p_ + 1] = (f16)hn_[1];                                \
    }                                                               \
    *(f16x4*)((DST) + c * 136 + jbase) = hv_;                       \
  }

// RK stage 4: h_new = tanh(h + (ksum+kk)/6) -> state + next stage-1 eval.
#define GATEF(DST)                                                  \
  {                                                                 \
    f16x4 hv_;                                                      \
    _Pragma("unroll") for (int p_ = 0; p_ < 2; ++p_) {              \
      f32x2 z_ = {ga[2 * p_], ga[2 * p_ + 1]};                      \
      f32x2 rr_ = {ra[2 * p_], ra[2 * p_ + 1]};                     \
      f32x2 th_ = tanh2_f(z_);                                      \
      f32x2 gt_ = sig2_f(th_);                                      \
      f32x2 kk_ = FMA2(gt_, rr_, FMA2(nitv2[p_], hhc2[p_], u2[p_])); \
      f32x2 ks_ = ksum2[p_] + kk_;                                  \
      f32x2 hn_ = tanh2_f(FMA2(B2(0.16666667f), ks_, hst2[p_]));    \
      hst2[p_] = hn_;                                               \
      hhc2[p_] = hn_;                                               \
      hv_[2 * p_] = (f16)hn_[0];                                    \
      hv_[2 * p_ + 1] = (f16)hn_[1];                                \
    }                                                               \
    *(f16x4*)((DST) + c * 136 + jbase) = hv_;                       \
  }

__global__ __launch_bounds__(1024, 1) void ltc_kernel(
    const float* __restrict__ seq, const float* __restrict__ ctx,
    const float* __restrict__ tau0p, const float* __restrict__ bg0p,
    const float* __restrict__ tau1p, const float* __restrict__ bg1p,
    const float* __restrict__ W1, const float* __restrict__ b1,
    const float* __restrict__ W2, const float* __restrict__ b2,
    const f16* __restrict__ W, float* __restrict__ out) {
  __shared__ __align__(16) char smem[SMEM_BYTES];
  f16* hq0 = (f16*)(smem + HQ0);
  f16* hq1 = (f16*)(smem + HQ1);
  f16* l0a = (f16*)(smem + L0A);
  f16* l0b = (f16*)(smem + L0B);
  f16* l1a = (f16*)(smem + L1A);
  f16* l1b = (f16*)(smem + L1B);
  f16* l1h = (f16*)(smem + L1H);
  f16* xt0 = (f16*)(smem + XT0);
  f16* xt1 = (f16*)(smem + XT1);

  const int tid = threadIdx.x;
  const int w16 = tid >> 6, lane = tid & 63;
  const int q = lane >> 4, c = lane & 15;
  const int wl = w16 & 7;  // row-tile T (0..7)
  const bool isL0 = (w16 < 8);
  const int bg = blockIdx.x;
  const int jbase = 16 * wl + 4 * q;  // this wave's tile, lane's 4 rows

  f16* bufA = isL0 ? l0a : l1a;
  f16* bufB = isL0 ? l0b : l1b;

  // ---- weight fragments -> VGPRs (held for whole kernel), 1 tile/wave ----
  f16x8 awg[4], awr[4], au[4], ag2[4];
  f16x8 bctx = (f16x8)(f16)0.f;
  if (isL0) {
#pragma unroll
    for (int kc = 0; kc < 4; ++kc) {
      awg[kc] = *(const f16x8*)(W + OFF_A0 + (((wl * 2 + 0) * 4 + kc) * 64 + lane) * 8);
      awr[kc] = *(const f16x8*)(W + OFF_A0 + (((wl * 2 + 1) * 4 + kc) * 64 + lane) * 8);
    }
#pragma unroll
    for (int kc = 0; kc < 3; ++kc) {
      au[kc] = *(const f16x8*)(W + OFF_AX + (((wl * 2 + 0) * 3 + kc) * 64 + lane) * 8);
      ag2[kc] = *(const f16x8*)(W + OFF_AX + (((wl * 2 + 1) * 3 + kc) * 64 + lane) * 8);
    }
    au[3] = (f16x8)(f16)0.f;
    ag2[3] = (f16x8)(f16)0.f;
    const float* cp = ctx + (bg * 16 + c) * 32 + 8 * q;
#pragma unroll
    for (int j = 0; j < 8; ++j) bctx[j] = (f16)cp[j];
  } else {
#pragma unroll
    for (int kc = 0; kc < 4; ++kc) {
      awg[kc] = *(const f16x8*)(W + OFF_A1 + (((wl * 2 + 0) * 4 + kc) * 64 + lane) * 8);
      awr[kc] = *(const f16x8*)(W + OFF_A1 + (((wl * 2 + 1) * 4 + kc) * 64 + lane) * 8);
      au[kc] = *(const f16x8*)(W + OFF_AIO + (((wl * 2 + 0) * 4 + kc) * 64 + lane) * 8);
      ag2[kc] = *(const f16x8*)(W + OFF_AIO + (((wl * 2 + 1) * 4 + kc) * 64 + lane) * 8);
    }
  }

  // per-lane params for the 4 owned rows (packed pairs, itv negated)
  const float* taup = isL0 ? tau0p : tau1p;
  const float* bgp = isL0 ? bg0p : bg1p;
  f32x2 nitv2[2];
  f32x4 bgv4;
#pragma unroll
  for (int r = 0; r < 4; ++r) {
    float t = taup[jbase + r];
    nitv2[r >> 1][r & 1] = -1.f / (logf(1.f + __expf(t)) + 1.f);
    bgv4[r] = bgp[jbase + r];
  }

  f32x2 hst2[2], hhc2[2], ksum2[2], u2[2];
  f32x4 ga, ra, gx4, un4, gxn4;
#pragma unroll
  for (int p = 0; p < 2; ++p) {
    hst2[p] = ZERO2;
    hhc2[p] = ZERO2;
    ksum2[p] = ZERO2;
    u2[p] = ZERO2;
  }
  gx4 = ZERO4;
  un4 = ZERO4;
  gxn4 = ZERO4;

  // zero initial-state buffers: hq1 (h0 at t=-1) and l1h (h1 at t=-1)
  for (int j = tid; j < 2176; j += 1024) {
    hq1[j] = (f16)0.f;
    l1h[j] = (f16)0.f;
  }
  // pre-stage x(0): 256 threads (all in L0 waves 0-3), float4 each
  const int bs = tid >> 4, fp = tid & 15;
  const size_t seqrow = ((size_t)(bg * 16 + bs)) * NSTEP * 64 + 4 * fp;
  float4 sq_nxt = {0.f, 0.f, 0.f, 0.f};
  float4 sq_ld = sq_nxt;
  if (tid < 256) {
    float4 sv = *(const float4*)(seq + seqrow);
    *(f16x4*)(xt0 + bs * 72 + 4 * fp) =
        (f16x4){(f16)sv.x, (f16)sv.y, (f16)sv.z, (f16)sv.w};
    sq_nxt = *(const float4*)(seq + seqrow + 64);  // x(1)
  }
  __syncthreads();
  // u/gx for step 0 (pipeline warm-up)
  if (isL0) {
    XPROJ(xt0, un4, gxn4);
    u2[0] = (f32x2){un4[0], un4[1]};
    u2[1] = (f32x2){un4[2], un4[3]};
    gx4 = gxn4;
  }

#pragma unroll 1
  for (int i = 0; i <= NSTEP; ++i) {
    const f16* hprev = ((i + 1) & 1) ? hq1 : hq0;  // h0(t-1) buffer
    f16* xw = ((i + 1) & 1) ? xt1 : xt0;           // buffer for x(i+1)

    // ===== slot A: L0 stage1 (+stage x(i+1), issue x(i+2)) | L1 io + stage1
    if (isL0) {
      if (i < NSTEP) {
        if (tid < 256 && i + 2 < NSTEP)
          sq_ld = *(const float4*)(seq + seqrow + (size_t)(i + 2) * 64);
        MM2G(hprev);  // stage 1 on h0(t-1) -- the critical prefix
        if (tid < 256 && i + 1 < NSTEP)
          *(f16x4*)(xw + bs * 72 + 4 * fp) =
              (f16x4){(f16)sq_nxt.x, (f16)sq_nxt.y, (f16)sq_nxt.z, (f16)sq_nxt.w};
        GATEP(1.0f, 0.5f, bufA, 1);
      }
    } else {
      if (i >= 1) {
        MMIO_B(hprev);  // u1 = Win1*h0_new, g1x = bg + Wg1x*h0_new
        u2[0] = (f32x2){ga[0], ga[1]};
        u2[1] = (f32x2){ga[2], ga[3]};
        gx4 = ra;
        MM2G(l1h);  // stage 1 on h1(t-2)
        GATEP(1.0f, 0.5f, bufA, 1);
      }
    }
    BAR();

    // ===== slot B: stage 2 ; L0 also computes x-proj(i+1) off-path =====
    if (isL0) {
      if (i < NSTEP) {
        MM2G(bufA);
        GATEP(2.0f, 0.5f, bufB, 0);
        if (i + 1 < NSTEP) { XPROJ(xw, un4, gxn4); }
      }
    } else if (i >= 1) {
      MM2G(bufA);
      GATEP(2.0f, 0.5f, bufB, 0);
    }
    BAR();

    // ===== slot C: stage 3 =====
    if ((isL0 && i < NSTEP) || (!isL0 && i >= 1)) {
      MM2G(bufB);
      GATEP(2.0f, 1.0f, bufA, 0);
    }
    BAR();

    // ===== slot D: stage 4 -> h_new; L0 commits pipelined u/gx + seq reg =====
    if (isL0) {
      if (i < NSTEP) {
        MM2G(bufA);
        GATEF((i & 1) ? hq1 : hq0);
        if (i + 1 < NSTEP) {
          u2[0] = (f32x2){un4[0], un4[1]};
          u2[1] = (f32x2){un4[2], un4[3]};
          gx4 = gxn4;
          if (i + 2 < NSTEP) sq_nxt = sq_ld;
        }
      }
    } else if (i >= 1) {
      MM2G(bufA);
      GATEF(l1h);
    }
    BAR();
  }

  // ======================= classifier epilogue ===========================
  float* h1f = (float*)smem;  // [16][132] f32
  if (!isL0) {
#pragma unroll
    for (int p = 0; p < 2; ++p)
      *(f32x2*)(h1f + c * 132 + jbase + 2 * p) = hst2[p];
  }
  __syncthreads();
  float* z1 = (float*)(smem + 16 * 132 * 4);  // [16][64] f32
  {
    int b = tid >> 5, o = tid & 31;
    if (b < 16) {
#pragma unroll
      for (int hlf = 0; hlf < 2; ++hlf) {
        int oo = o + 32 * hlf;
        const float* wr = W1 + oo * 128;
        const float* hr = h1f + b * 132;
        float s = 0.f;
#pragma unroll
        for (int j = 0; j < 128; j += 4) {
          f32x4 wv = *(const f32x4*)(wr + j);
          f32x4 hv = *(const f32x4*)(hr + j);
          s += wv[0] * hv[0] + wv[1] * hv[1] + wv[2] * hv[2] + wv[3] * hv[3];
        }
        s += b1[oo];
        z1[b * 64 + oo] = fmaxf(s, 0.f);
      }
    }
  }
  __syncthreads();
  if (tid < 16) {
    float s = b2[0];
#pragma unroll
    for (int o = 0; o < 64; ++o) s += z1[tid * 64 + o] * W2[o];
    out[bg * 16 + tid] = rcp_f(1.f + __expf(-s));
  }
}

extern "C" void kernel_launch(void* const* d_in, const int* in_sizes, int n_in,
                              void* d_out, int out_size, void* d_ws, size_t ws_size,
                              hipStream_t stream) {
  (void)in_sizes; (void)n_in; (void)out_size; (void)ws_size;
  const float* seq = (const float*)d_in[0];
  const float* ctx = (const float*)d_in[1];
  const float* tau0 = (const float*)d_in[2];
  const float* Win0 = (const float*)d_in[3];
  const float* Wrec0 = (const float*)d_in[4];
  const float* Wg0 = (const float*)d_in[5];
  const float* bg0 = (const float*)d_in[6];
  const float* tau1 = (const float*)d_in[7];
  const float* Win1 = (const float*)d_in[8];
  const float* Wrec1 = (const float*)d_in[9];
  const float* Wg1 = (const float*)d_in[10];
  const float* bg1 = (const float*)d_in[11];
  const float* W1 = (const float*)d_in[12];
  const float* b1 = (const float*)d_in[13];
  const float* W2 = (const float*)d_in[14];
  const float* b2 = (const float*)d_in[15];
  f16* W = (f16*)d_ws;  // 245760 B of packed fragments

  prep_kernel<<<480, 256, 0, stream>>>(Win0, Wrec0, Wg0, Win1, Wrec1, Wg1, W);
  ltc_kernel<<<32, 1024, 0, stream>>>(seq, ctx, tau0, bg0, tau1, bg1, W1, b1,
                                      W2, b2, W, (float*)d_out);
}